// Round 4
// baseline (720.362 us; speedup 1.0000x reference)
//
#include <hip/hip_runtime.h>

#define NTOK 4096
#define NEXP 8
#define HD 2048
#define ID 1408

typedef unsigned short u16;
typedef __attribute__((ext_vector_type(8))) short short8;
typedef __attribute__((ext_vector_type(4))) short short4v;
typedef __attribute__((ext_vector_type(4))) float f32x4;
typedef const __attribute__((address_space(1))) void* gas_ptr;
typedef __attribute__((address_space(3))) void* las_ptr;

__device__ __forceinline__ u16 f2bf(float f) {
  unsigned int u = __float_as_uint(f);
  u += 0x7FFFu + ((u >> 16) & 1u);   // RNE
  return (u16)(u >> 16);
}
__device__ __forceinline__ float bf2f(u16 v) {
  return __uint_as_float((unsigned int)v << 16);
}

__device__ __forceinline__ void async16(const u16* g, u16* l) {
  __builtin_amdgcn_global_load_lds((gas_ptr)g, (las_ptr)l, 16, 0, 0);
}

// fp32 -> bf16 bulk convert for the 3 weight tensors in one launch.
__global__ void cvt3_kernel(const float* __restrict__ s0, const float* __restrict__ s1,
                            const float* __restrict__ s2, u16* __restrict__ d0,
                            u16* __restrict__ d1, u16* __restrict__ d2, long n8each) {
  long i = (long)blockIdx.x * blockDim.x + threadIdx.x;
  const float* s; u16* d; long j;
  if (i < n8each)            { s = s0; d = d0; j = i; }
  else if (i < 2*n8each)     { s = s1; d = d1; j = i - n8each; }
  else if (i < 3*n8each)     { s = s2; d = d2; j = i - 2*n8each; }
  else return;
  const float4* s4 = (const float4*)s;
  float4 a = s4[2*j], b = s4[2*j+1];
  short8 o;
  o[0] = (short)f2bf(a.x); o[1] = (short)f2bf(a.y);
  o[2] = (short)f2bf(a.z); o[3] = (short)f2bf(a.w);
  o[4] = (short)f2bf(b.x); o[5] = (short)f2bf(b.y);
  o[6] = (short)f2bf(b.z); o[7] = (short)f2bf(b.w);
  *(short8*)(d + 8*j) = o;
}

// router: logits (fp32), softmax, top-2, per-expert scatter lists.
// Also converts x -> bf16 (xb) on the way through.
__global__ void router_kernel(const float* __restrict__ x, const float* __restrict__ gw,
                              u16* __restrict__ xb,
                              float* __restrict__ logits, int* __restrict__ cnt,
                              int* __restrict__ ptok, float* __restrict__ pw) {
  int t = blockIdx.x * 4 + (threadIdx.x >> 6);   // one wave per token
  int lane = threadIdx.x & 63;
  if (t >= NTOK) return;
  const float4* xr = (const float4*)(x + (size_t)t * HD);
  u16* xbr = xb + (size_t)t * HD;
  float dot[NEXP];
#pragma unroll
  for (int e = 0; e < NEXP; ++e) dot[e] = 0.f;
#pragma unroll
  for (int c = 0; c < 8; ++c) {                  // 2048/4/64 = 8 chunks
    float4 xv = xr[c*64 + lane];
    short4v o;
    o[0] = (short)f2bf(xv.x); o[1] = (short)f2bf(xv.y);
    o[2] = (short)f2bf(xv.z); o[3] = (short)f2bf(xv.w);
    *(short4v*)(xbr + (c*64 + lane)*4) = o;
#pragma unroll
    for (int e = 0; e < NEXP; ++e) {
      float4 gv = ((const float4*)(gw + e*HD))[c*64 + lane];
      dot[e] += xv.x*gv.x + xv.y*gv.y + xv.z*gv.z + xv.w*gv.w;
    }
  }
#pragma unroll
  for (int off = 32; off > 0; off >>= 1) {
#pragma unroll
    for (int e = 0; e < NEXP; ++e) dot[e] += __shfl_xor(dot[e], off);
  }
  if (lane < NEXP) logits[(size_t)t*NEXP + lane] = dot[lane];
  if (lane == 0) {
    float mx = dot[0];
#pragma unroll
    for (int e = 1; e < NEXP; ++e) mx = fmaxf(mx, dot[e]);
    float p[NEXP];
#pragma unroll
    for (int e = 0; e < NEXP; ++e) p[e] = __expf(dot[e] - mx);
    int e0 = 0;
#pragma unroll
    for (int e = 1; e < NEXP; ++e) if (p[e] > p[e0]) e0 = e;   // ties -> lowest idx
    int e1 = (e0 == 0) ? 1 : 0;
#pragma unroll
    for (int e = 0; e < NEXP; ++e) if (e != e0 && p[e] > p[e1]) e1 = e;
    float denom = p[e0] + p[e1];
    int pos0 = atomicAdd(&cnt[e0], 1);
    ptok[e0*NTOK + pos0] = t; pw[e0*NTOK + pos0] = p[e0] / denom;
    int pos1 = atomicAdd(&cnt[e1], 1);
    ptok[e1*NTOK + pos1] = t; pw[e1*NTOK + pos1] = p[e1] / denom;
  }
}

__global__ void prefix_kernel(const int* __restrict__ cnt, int* __restrict__ offs) {
  if (threadIdx.x == 0) {
    int a = 0;
    for (int e = 0; e < NEXP; ++e) { offs[e] = a; a += cnt[e]; }
  }
}

// ---------------------------------------------------------------------------
// Shared counted-vmcnt double-buffered K-loop (T3+T4+T5).
// 128x128 tile, BK=64, 4 waves. LDS [128][64] per tensor, XOR-swizzled
// (linear gload_lds dest + inverse-swizzled GLOBAL source + swizzled read).
// Per K-step: 2 phases of {ds_read half, barrier, setprio+16 MFMA, barrier};
// next-tile ISSUE after the all-reads barrier; gate = vmcnt(8) (counted, never
// 0 in steady state) so the prefetch batch stays in flight across barriers.
// ---------------------------------------------------------------------------
template<int NT>
__device__ __forceinline__ void kloop(
    const u16* const ga[4], const u16* const gb[4],
    u16* sA, u16* sB, int tid, int fm, int kg, int wr, int wc,
    f32x4 (&acc)[4][4])
{
  const int sw = fm & 7;
  const int ar = wr*64 + fm;
  const int br = wc*64 + fm;

#define ISSUE(buf, k0) do { \
    _Pragma("unroll") \
    for (int p = 0; p < 4; ++p) { \
      async16(ga[p] + (k0), sA + (buf)*8192 + p*2048 + tid*8); \
      async16(gb[p] + (k0), sB + (buf)*8192 + p*2048 + tid*8); \
    } } while (0)

  ISSUE(0, 0);
  ISSUE(1, 64);
  asm volatile("s_waitcnt vmcnt(8)" ::: "memory");   // batch 0 landed; batch 1 in flight
  asm volatile("s_barrier" ::: "memory");

  for (int t = 0; t < NT; ++t) {
    const u16* bA = sA + (t & 1) * 8192;
    const u16* bB = sB + (t & 1) * 8192;
    // ---- phase 0 (k-half 0)
    short8 a0[4], b0[4];
    {
      int co = (kg ^ sw) * 8;
#pragma unroll
      for (int i = 0; i < 4; ++i) a0[i] = *(const short8*)(bA + (ar + i*16)*64 + co);
#pragma unroll
      for (int j = 0; j < 4; ++j) b0[j] = *(const short8*)(bB + (br + j*16)*64 + co);
    }
    asm volatile("s_barrier" ::: "memory");
    __builtin_amdgcn_s_setprio(1);
#pragma unroll
    for (int i = 0; i < 4; ++i)
#pragma unroll
      for (int j = 0; j < 4; ++j)
        acc[i][j] = __builtin_amdgcn_mfma_f32_16x16x32_bf16(a0[i], b0[j], acc[i][j], 0, 0, 0);
    __builtin_amdgcn_s_setprio(0);
    asm volatile("s_barrier" ::: "memory");
    // ---- phase 1 (k-half 1)
    short8 a1[4], b1[4];
    {
      int co = ((kg + 4) ^ sw) * 8;
#pragma unroll
      for (int i = 0; i < 4; ++i) a1[i] = *(const short8*)(bA + (ar + i*16)*64 + co);
#pragma unroll
      for (int j = 0; j < 4; ++j) b1[j] = *(const short8*)(bB + (br + j*16)*64 + co);
    }
    asm volatile("s_barrier" ::: "memory");   // all waves done reading buf (t&1)
    if (t + 2 < NT) ISSUE((t & 1), (t + 2) * 64);   // overwrite is now safe
    __builtin_amdgcn_s_setprio(1);
#pragma unroll
    for (int i = 0; i < 4; ++i)
#pragma unroll
      for (int j = 0; j < 4; ++j)
        acc[i][j] = __builtin_amdgcn_mfma_f32_16x16x32_bf16(a1[i], b1[j], acc[i][j], 0, 0, 0);
    __builtin_amdgcn_s_setprio(0);
    if (t < NT - 2)       asm volatile("s_waitcnt vmcnt(8)" ::: "memory"); // t+1 landed, t+2 flying
    else if (t == NT - 2) asm volatile("s_waitcnt vmcnt(0)" ::: "memory"); // drain final batch
    asm volatile("s_barrier" ::: "memory");
  }
#undef ISSUE
}

// GEMM-G: g = x@wg^T  -> hbuf (bf16)
__global__ __launch_bounds__(256, 2) void gemmg_kernel(
    const u16* __restrict__ xb, const u16* __restrict__ wgb,
    const int* __restrict__ cnt, const int* __restrict__ offs,
    const int* __restrict__ ptok, u16* __restrict__ hbuf) {
  int e = blockIdx.z, mt = blockIdx.y, nt = blockIdx.x;
  int c = cnt[e];
  if (mt * 128 >= c) return;
  int off = offs[e];

  __shared__ u16 sA[2*128*64], sB[2*128*64];   // 2 x 32 KB

  int tid = threadIdx.x;
  int r  = tid >> 3;                 // staging row within 32-row slab
  int cq = tid & 7;                  // dest chunk
  int cx = (cq ^ (r & 7)) * 8;       // inverse-swizzled global chunk

  const u16* ga[4];
#pragma unroll
  for (int p = 0; p < 4; ++p) {
    int s = mt*128 + r + p*32;
    int t = ptok[e*NTOK + (s < c ? s : 0)];
    ga[p] = xb + (size_t)t*HD + cx;
  }
  const u16* gb[4];
#pragma unroll
  for (int p = 0; p < 4; ++p)
    gb[p] = wgb + ((size_t)e*ID + nt*128 + r + p*32)*HD + cx;

  int lane = tid & 63, wv = tid >> 6, wr = wv >> 1, wc = wv & 1;
  int fm = lane & 15, kg = lane >> 4;

  f32x4 acc[4][4];
#pragma unroll
  for (int i = 0; i < 4; ++i)
#pragma unroll
    for (int j = 0; j < 4; ++j) acc[i][j] = {0.f, 0.f, 0.f, 0.f};

  kloop<HD/64>(ga, gb, sA, sB, tid, fm, kg, wr, wc, acc);

#pragma unroll
  for (int i = 0; i < 4; ++i) {
#pragma unroll
    for (int rr = 0; rr < 4; ++rr) {
      int slot = mt*128 + wr*64 + i*16 + kg*4 + rr;
      if (slot < c) {
        size_t rowb = (size_t)(off + slot) * ID + nt*128 + wc*64 + fm;
#pragma unroll
        for (int j = 0; j < 4; ++j)
          hbuf[rowb + (size_t)j*16] = f2bf(acc[i][j][rr]);
      }
    }
  }
}

// GEMM-U: u = x@wu^T; epilogue reads g from hbuf, rewrites h = silu(g)*u in place.
__global__ __launch_bounds__(256, 2) void gemmu_kernel(
    const u16* __restrict__ xb, const u16* __restrict__ wub,
    const int* __restrict__ cnt, const int* __restrict__ offs,
    const int* __restrict__ ptok, u16* __restrict__ hbuf) {
  int e = blockIdx.z, mt = blockIdx.y, nt = blockIdx.x;
  int c = cnt[e];
  if (mt * 128 >= c) return;
  int off = offs[e];

  __shared__ u16 sA[2*128*64], sB[2*128*64];

  int tid = threadIdx.x;
  int r  = tid >> 3;
  int cq = tid & 7;
  int cx = (cq ^ (r & 7)) * 8;

  const u16* ga[4];
#pragma unroll
  for (int p = 0; p < 4; ++p) {
    int s = mt*128 + r + p*32;
    int t = ptok[e*NTOK + (s < c ? s : 0)];
    ga[p] = xb + (size_t)t*HD + cx;
  }
  const u16* gb[4];
#pragma unroll
  for (int p = 0; p < 4; ++p)
    gb[p] = wub + ((size_t)e*ID + nt*128 + r + p*32)*HD + cx;

  int lane = tid & 63, wv = tid >> 6, wr = wv >> 1, wc = wv & 1;
  int fm = lane & 15, kg = lane >> 4;

  f32x4 acc[4][4];
#pragma unroll
  for (int i = 0; i < 4; ++i)
#pragma unroll
    for (int j = 0; j < 4; ++j) acc[i][j] = {0.f, 0.f, 0.f, 0.f};

  kloop<HD/64>(ga, gb, sA, sB, tid, fm, kg, wr, wc, acc);

#pragma unroll
  for (int i = 0; i < 4; ++i) {
#pragma unroll
    for (int rr = 0; rr < 4; ++rr) {
      int slot = mt*128 + wr*64 + i*16 + kg*4 + rr;
      if (slot < c) {
        size_t rowb = (size_t)(off + slot) * ID + nt*128 + wc*64 + fm;
#pragma unroll
        for (int j = 0; j < 4; ++j) {
          float g32 = bf2f(hbuf[rowb + (size_t)j*16]);
          float uv  = acc[i][j][rr];
          float hh  = g32 * uv / (1.f + __expf(-g32));   // silu(g)*u
          hbuf[rowb + (size_t)j*16] = f2bf(hh);
        }
      }
    }
  }
}

// GEMM-D: y = h @ wd^T, weighted atomic scatter into out.
__global__ __launch_bounds__(256, 2) void gemmd_kernel(
    const u16* __restrict__ hbuf, const u16* __restrict__ wdb,
    const int* __restrict__ cnt, const int* __restrict__ offs,
    const int* __restrict__ ptok, const float* __restrict__ pw,
    float* __restrict__ out) {
  int e = blockIdx.z, mt = blockIdx.y, nt = blockIdx.x;
  int c = cnt[e];
  if (mt * 128 >= c) return;
  int off = offs[e];

  __shared__ u16 sA[2*128*64], sB[2*128*64];

  int tid = threadIdx.x;
  int r  = tid >> 3;
  int cq = tid & 7;
  int cx = (cq ^ (r & 7)) * 8;

  const u16* ga[4];
#pragma unroll
  for (int p = 0; p < 4; ++p) {
    int s = mt*128 + r + p*32;
    ga[p] = hbuf + (size_t)(off + (s < c ? s : 0))*ID + cx;
  }
  const u16* gb[4];
#pragma unroll
  for (int p = 0; p < 4; ++p)
    gb[p] = wdb + ((size_t)e*HD + nt*128 + r + p*32)*ID + cx;

  int lane = tid & 63, wv = tid >> 6, wr = wv >> 1, wc = wv & 1;
  int fm = lane & 15, kg = lane >> 4;

  f32x4 acc[4][4];
#pragma unroll
  for (int i = 0; i < 4; ++i)
#pragma unroll
    for (int j = 0; j < 4; ++j) acc[i][j] = {0.f, 0.f, 0.f, 0.f};

  kloop<ID/64>(ga, gb, sA, sB, tid, fm, kg, wr, wc, acc);

#pragma unroll
  for (int i = 0; i < 4; ++i) {
#pragma unroll
    for (int rr = 0; rr < 4; ++rr) {
      int slot = mt*128 + wr*64 + i*16 + kg*4 + rr;
      if (slot < c) {
        int tok = ptok[e*NTOK + slot];
        float wgt = pw[e*NTOK + slot];
        float* orow = out + (size_t)tok*HD + nt*128 + wc*64 + fm;
#pragma unroll
        for (int j = 0; j < 4; ++j)
          atomicAdd(orow + j*16, wgt * acc[i][j][rr]);
      }
    }
  }
}

extern "C" void kernel_launch(void* const* d_in, const int* in_sizes, int n_in,
                              void* d_out, int out_size, void* d_ws, size_t ws_size,
                              hipStream_t stream) {
  const float* x  = (const float*)d_in[0];
  const float* gw = (const float*)d_in[1];
  const float* wg = (const float*)d_in[2];
  const float* wu = (const float*)d_in[3];
  const float* wd = (const float*)d_in[4];
  float* out = (float*)d_out;

  // workspace carve (bytes), all 16B-aligned
  char* p = (char*)d_ws;
  u16*   xb   = (u16*)(p);                    //  16,777,216 B : x bf16 [4096,2048]
  u16*   wgb  = (u16*)(p + 16777216UL);       //  46,137,344 B : wg bf16
  u16*   wub  = (u16*)(p + 62914560UL);       //  46,137,344 B : wu bf16
  u16*   wdb  = (u16*)(p + 109051904UL);      //  46,137,344 B : wd bf16
  u16*   hbuf = (u16*)(p + 155189248UL);      //  23,068,672 B : g then h bf16 [8192,1408]
  int*   ptok = (int*)(p + 178257920UL);      //     131,072 B
  float* pww  = (float*)(p + 178388992UL);    //     131,072 B
  int*   cnt  = (int*)(p + 178520064UL);      //         256 B
  int*   offs = (int*)(p + 178520320UL);      //         256 B

  hipMemsetAsync(out, 0, (size_t)NTOK * HD * sizeof(float), stream);
  hipMemsetAsync(cnt, 0, NEXP * sizeof(int), stream);

  long n8each = (long)NEXP * ID * HD / 8;     // 2,883,584
  cvt3_kernel<<<33792, 256, 0, stream>>>(wg, wu, wd, wgb, wub, wdb, n8each);

  router_kernel<<<1024, 256, 0, stream>>>(x, gw, xb, out + (size_t)NTOK * HD, cnt, ptok, pww);
  prefix_kernel<<<1, 64, 0, stream>>>(cnt, offs);

  gemmg_kernel<<<dim3(11, 32, 8), 256, 0, stream>>>(xb, wgb, cnt, offs, ptok, hbuf);
  gemmu_kernel<<<dim3(11, 32, 8), 256, 0, stream>>>(xb, wub, cnt, offs, ptok, hbuf);
  gemmd_kernel<<<dim3(16, 32, 8), 256, 0, stream>>>(hbuf, wdb, cnt, offs, ptok, pww, out);
}

// Round 5
// 688.954 us; speedup vs baseline: 1.0456x; 1.0456x over previous
//
#include <hip/hip_runtime.h>

#define NTOK 4096
#define NEXP 8
#define HD 2048
#define ID 1408

typedef unsigned short u16;
typedef __attribute__((ext_vector_type(8))) short short8;
typedef __attribute__((ext_vector_type(4))) short short4v;
typedef __attribute__((ext_vector_type(4))) float f32x4;
typedef const __attribute__((address_space(1))) void* gas_ptr;
typedef __attribute__((address_space(3))) void* las_ptr;

__device__ __forceinline__ u16 f2bf(float f) {
  unsigned int u = __float_as_uint(f);
  u += 0x7FFFu + ((u >> 16) & 1u);   // RNE
  return (u16)(u >> 16);
}

__device__ __forceinline__ void async16(const u16* g, u16* l) {
  __builtin_amdgcn_global_load_lds((gas_ptr)g, (las_ptr)l, 16, 0, 0);
}

// fp32 -> bf16 bulk convert for the 3 weight tensors in one launch.
__global__ void cvt3_kernel(const float* __restrict__ s0, const float* __restrict__ s1,
                            const float* __restrict__ s2, u16* __restrict__ d0,
                            u16* __restrict__ d1, u16* __restrict__ d2, long n8each) {
  long i = (long)blockIdx.x * blockDim.x + threadIdx.x;
  const float* s; u16* d; long j;
  if (i < n8each)            { s = s0; d = d0; j = i; }
  else if (i < 2*n8each)     { s = s1; d = d1; j = i - n8each; }
  else if (i < 3*n8each)     { s = s2; d = d2; j = i - 2*n8each; }
  else return;
  const float4* s4 = (const float4*)s;
  float4 a = s4[2*j], b = s4[2*j+1];
  short8 o;
  o[0] = (short)f2bf(a.x); o[1] = (short)f2bf(a.y);
  o[2] = (short)f2bf(a.z); o[3] = (short)f2bf(a.w);
  o[4] = (short)f2bf(b.x); o[5] = (short)f2bf(b.y);
  o[6] = (short)f2bf(b.z); o[7] = (short)f2bf(b.w);
  *(short8*)(d + 8*j) = o;
}

// router: logits (fp32), softmax, top-2, per-expert scatter lists.
// Also converts x -> bf16 (xb) on the way through.
__global__ void router_kernel(const float* __restrict__ x, const float* __restrict__ gw,
                              u16* __restrict__ xb,
                              float* __restrict__ logits, int* __restrict__ cnt,
                              int* __restrict__ ptok, float* __restrict__ pw) {
  int t = blockIdx.x * 4 + (threadIdx.x >> 6);   // one wave per token
  int lane = threadIdx.x & 63;
  if (t >= NTOK) return;
  const float4* xr = (const float4*)(x + (size_t)t * HD);
  u16* xbr = xb + (size_t)t * HD;
  float dot[NEXP];
#pragma unroll
  for (int e = 0; e < NEXP; ++e) dot[e] = 0.f;
#pragma unroll
  for (int c = 0; c < 8; ++c) {                  // 2048/4/64 = 8 chunks
    float4 xv = xr[c*64 + lane];
    short4v o;
    o[0] = (short)f2bf(xv.x); o[1] = (short)f2bf(xv.y);
    o[2] = (short)f2bf(xv.z); o[3] = (short)f2bf(xv.w);
    *(short4v*)(xbr + (c*64 + lane)*4) = o;
#pragma unroll
    for (int e = 0; e < NEXP; ++e) {
      float4 gv = ((const float4*)(gw + e*HD))[c*64 + lane];
      dot[e] += xv.x*gv.x + xv.y*gv.y + xv.z*gv.z + xv.w*gv.w;
    }
  }
#pragma unroll
  for (int off = 32; off > 0; off >>= 1) {
#pragma unroll
    for (int e = 0; e < NEXP; ++e) dot[e] += __shfl_xor(dot[e], off);
  }
  if (lane < NEXP) logits[(size_t)t*NEXP + lane] = dot[lane];
  if (lane == 0) {
    float mx = dot[0];
#pragma unroll
    for (int e = 1; e < NEXP; ++e) mx = fmaxf(mx, dot[e]);
    float p[NEXP];
#pragma unroll
    for (int e = 0; e < NEXP; ++e) p[e] = __expf(dot[e] - mx);
    int e0 = 0;
#pragma unroll
    for (int e = 1; e < NEXP; ++e) if (p[e] > p[e0]) e0 = e;   // ties -> lowest idx
    int e1 = (e0 == 0) ? 1 : 0;
#pragma unroll
    for (int e = 0; e < NEXP; ++e) if (e != e0 && p[e] > p[e1]) e1 = e;
    float denom = p[e0] + p[e1];
    int pos0 = atomicAdd(&cnt[e0], 1);
    ptok[e0*NTOK + pos0] = t; pw[e0*NTOK + pos0] = p[e0] / denom;
    int pos1 = atomicAdd(&cnt[e1], 1);
    ptok[e1*NTOK + pos1] = t; pw[e1*NTOK + pos1] = p[e1] / denom;
  }
}

__global__ void prefix_kernel(const int* __restrict__ cnt, int* __restrict__ offs) {
  if (threadIdx.x == 0) {
    int a = 0;
    for (int e = 0; e < NEXP; ++e) { offs[e] = a; a += cnt[e]; }
  }
}

// ---------------------------------------------------------------------------
// 256x128 tile, BK=64, 8 waves (4 row-waves x 2 col-waves), wave tile 64x64.
// LDS XOR-swizzled as in r3 (proven conflicts=0): linear gload_lds dest +
// inverse-swizzled GLOBAL source + swizzled read.
// T3-minimum loop: STAGE(t+1) at tile top -> reads+MFMA on tile t -> ONE
// gate+barrier per tile, so staging flies across the whole tile's compute.
// NSTG=2: gate = __syncthreads (vmcnt(0) drains exactly the next tile's loads).
// NSTG=3: counted gate vmcnt(6) (depth-2 pipeline, never drains in steady state).
// ---------------------------------------------------------------------------
template<int NT, int NSTG, int DUAL>
__device__ __forceinline__ void kloop256(
    const u16* const ga[4], const u16* const gb0[2], const u16* const gb1[2],
    u16* sA, u16* sB0, u16* sB1,
    int tid, int wr, int wc, int fm, int kg,
    f32x4 (&acc0)[4][4], f32x4 (&acc1)[4][4])
{
  const int swz = fm & 7;

#define STG(st, k0) do { \
    _Pragma("unroll") \
    for (int q = 0; q < 4; ++q) \
      async16(ga[q] + (k0), sA + (st)*16384 + q*4096 + tid*8); \
    _Pragma("unroll") \
    for (int q = 0; q < 2; ++q) \
      async16(gb0[q] + (k0), sB0 + (st)*8192 + q*4096 + tid*8); \
    if (DUAL) { \
      _Pragma("unroll") \
      for (int q = 0; q < 2; ++q) \
        async16(gb1[q] + (k0), sB1 + (st)*8192 + q*4096 + tid*8); \
    } } while (0)

  STG(0, 0);
  if (NSTG == 3) {
    STG(1, 64);
    asm volatile("s_waitcnt vmcnt(6)" ::: "memory");   // stage 0 landed, stage 1 flying
    __builtin_amdgcn_s_barrier();
    __builtin_amdgcn_sched_barrier(0);
  } else {
    __syncthreads();                                    // full drain (stage 0 only)
  }

  for (int t = 0; t < NT; ++t) {
    int pre = t + NSTG - 1;
    if (pre < NT) STG(pre % NSTG, pre * 64);            // overlaps this tile's compute
    const u16* bA  = sA  + (t % NSTG) * 16384;
    const u16* bB0 = sB0 + (t % NSTG) * 8192;
    const u16* bB1 = sB1 + (t % NSTG) * 8192;
#pragma unroll
    for (int ks = 0; ks < 2; ++ks) {
      int co = ((ks*4 + kg) ^ swz) * 8;
      short8 av[4], b0[4], b1[4];
#pragma unroll
      for (int j = 0; j < 4; ++j) {
        b0[j] = *(const short8*)(bB0 + (wc*64 + j*16 + fm)*64 + co);
        if (DUAL) b1[j] = *(const short8*)(bB1 + (wc*64 + j*16 + fm)*64 + co);
      }
#pragma unroll
      for (int i = 0; i < 4; ++i)
        av[i] = *(const short8*)(bA + (wr*64 + i*16 + fm)*64 + co);
      __builtin_amdgcn_s_setprio(1);
#pragma unroll
      for (int i = 0; i < 4; ++i)
#pragma unroll
        for (int j = 0; j < 4; ++j) {
          acc0[i][j] = __builtin_amdgcn_mfma_f32_16x16x32_bf16(av[i], b0[j], acc0[i][j], 0, 0, 0);
          if (DUAL)
            acc1[i][j] = __builtin_amdgcn_mfma_f32_16x16x32_bf16(av[i], b1[j], acc1[i][j], 0, 0, 0);
        }
      __builtin_amdgcn_s_setprio(0);
    }
    if (t + 1 < NT) {
      if (NSTG == 3 && t + 2 < NT) {
        asm volatile("s_waitcnt vmcnt(6)" ::: "memory"); // t+1 landed, t+2 flying
        __builtin_amdgcn_s_barrier();
        __builtin_amdgcn_sched_barrier(0);
      } else if (NSTG == 3) {
        asm volatile("s_waitcnt vmcnt(0)" ::: "memory");
        __builtin_amdgcn_s_barrier();
        __builtin_amdgcn_sched_barrier(0);
      } else {
        __syncthreads();                                 // drains exactly t+1's loads
      }
    }
  }
#undef STG
}

// GEMM1: h = silu(x@wg^T) * (x@wu^T), fused dual-B, rows gathered via ptok.
__global__ __launch_bounds__(512, 2) void gemm1_kernel(
    const u16* __restrict__ xb, const u16* __restrict__ wgb, const u16* __restrict__ wub,
    const int* __restrict__ cnt, const int* __restrict__ offs,
    const int* __restrict__ ptok, u16* __restrict__ hbuf) {
  int e = blockIdx.z, mt = blockIdx.y, nt = blockIdx.x;
  int c = cnt[e];
  if (mt * 256 >= c) return;
  int off = offs[e];

  __shared__ u16 sA[2*256*64], sBg[2*128*64], sBu[2*128*64];   // 64+32+32 = 128 KB

  int tid = threadIdx.x;
  int r5 = tid >> 3;                 // row within 64-row slab
  int cq = tid & 7;
  int cx = (cq ^ (r5 & 7)) * 8;      // inverse-swizzled global chunk

  const u16* ga[4];
#pragma unroll
  for (int q = 0; q < 4; ++q) {
    int s = mt*256 + q*64 + r5;
    int t = ptok[e*NTOK + (s < c ? s : 0)];
    ga[q] = xb + (size_t)t*HD + cx;
  }
  const u16* gbg[2];
  const u16* gbu[2];
#pragma unroll
  for (int q = 0; q < 2; ++q) {
    int n = nt*128 + q*64 + r5;
    gbg[q] = wgb + ((size_t)e*ID + n)*HD + cx;
    gbu[q] = wub + ((size_t)e*ID + n)*HD + cx;
  }

  int lane = tid & 63, wv = tid >> 6, wr = wv >> 1, wc = wv & 1;
  int fm = lane & 15, kg = lane >> 4;

  f32x4 accg[4][4], accu[4][4];
#pragma unroll
  for (int i = 0; i < 4; ++i)
#pragma unroll
    for (int j = 0; j < 4; ++j) {
      accg[i][j] = {0.f, 0.f, 0.f, 0.f};
      accu[i][j] = {0.f, 0.f, 0.f, 0.f};
    }

  kloop256<HD/64, 2, 1>(ga, gbg, gbu, sA, sBg, sBu, tid, wr, wc, fm, kg, accg, accu);

#pragma unroll
  for (int i = 0; i < 4; ++i) {
#pragma unroll
    for (int rr = 0; rr < 4; ++rr) {
      int slot = mt*256 + wr*64 + i*16 + kg*4 + rr;
      if (slot < c) {
        size_t rowb = (size_t)(off + slot) * ID + nt*128 + wc*64 + fm;
#pragma unroll
        for (int j = 0; j < 4; ++j) {
          float gv = accg[i][j][rr], uv = accu[i][j][rr];
          float hh = gv * uv / (1.f + __expf(-gv));   // silu(g)*u
          hbuf[rowb + (size_t)j*16] = f2bf(hh);
        }
      }
    }
  }
}

// GEMM2: y = h @ wd^T, weighted atomic scatter into out. 3-stage counted pipeline.
__global__ __launch_bounds__(512, 2) void gemm2_kernel(
    const u16* __restrict__ hbuf, const u16* __restrict__ wdb,
    const int* __restrict__ cnt, const int* __restrict__ offs,
    const int* __restrict__ ptok, const float* __restrict__ pw,
    float* __restrict__ out) {
  int e = blockIdx.z, mt = blockIdx.y, nt = blockIdx.x;
  int c = cnt[e];
  if (mt * 256 >= c) return;
  int off = offs[e];

  __shared__ u16 sA[3*256*64], sB[3*128*64];   // 96+48 = 144 KB

  int tid = threadIdx.x;
  int r5 = tid >> 3;
  int cq = tid & 7;
  int cx = (cq ^ (r5 & 7)) * 8;

  const u16* ga[4];
#pragma unroll
  for (int q = 0; q < 4; ++q) {
    int s = mt*256 + q*64 + r5;
    ga[q] = hbuf + (size_t)(off + (s < c ? s : 0))*ID + cx;
  }
  const u16* gb[2];
#pragma unroll
  for (int q = 0; q < 2; ++q) {
    int n = nt*128 + q*64 + r5;
    gb[q] = wdb + ((size_t)e*HD + n)*ID + cx;
  }

  int lane = tid & 63, wv = tid >> 6, wr = wv >> 1, wc = wv & 1;
  int fm = lane & 15, kg = lane >> 4;

  f32x4 acc[4][4], dummy[4][4];
#pragma unroll
  for (int i = 0; i < 4; ++i)
#pragma unroll
    for (int j = 0; j < 4; ++j) acc[i][j] = {0.f, 0.f, 0.f, 0.f};

  kloop256<ID/64, 3, 0>(ga, gb, gb, sA, sB, sB, tid, wr, wc, fm, kg, acc, dummy);

#pragma unroll
  for (int i = 0; i < 4; ++i) {
#pragma unroll
    for (int rr = 0; rr < 4; ++rr) {
      int slot = mt*256 + wr*64 + i*16 + kg*4 + rr;
      if (slot < c) {
        int tok = ptok[e*NTOK + slot];
        float wgt = pw[e*NTOK + slot];
        float* orow = out + (size_t)tok*HD + nt*128 + wc*64 + fm;
#pragma unroll
        for (int j = 0; j < 4; ++j)
          atomicAdd(orow + j*16, wgt * acc[i][j][rr]);
      }
    }
  }
}

extern "C" void kernel_launch(void* const* d_in, const int* in_sizes, int n_in,
                              void* d_out, int out_size, void* d_ws, size_t ws_size,
                              hipStream_t stream) {
  const float* x  = (const float*)d_in[0];
  const float* gw = (const float*)d_in[1];
  const float* wg = (const float*)d_in[2];
  const float* wu = (const float*)d_in[3];
  const float* wd = (const float*)d_in[4];
  float* out = (float*)d_out;

  // workspace carve (bytes), all 16B-aligned
  char* p = (char*)d_ws;
  u16*   xb   = (u16*)(p);                    //  16,777,216 B : x bf16 [4096,2048]
  u16*   wgb  = (u16*)(p + 16777216UL);       //  46,137,344 B : wg bf16
  u16*   wub  = (u16*)(p + 62914560UL);       //  46,137,344 B : wu bf16
  u16*   wdb  = (u16*)(p + 109051904UL);      //  46,137,344 B : wd bf16
  u16*   hbuf = (u16*)(p + 155189248UL);      //  23,068,672 B : h bf16 [8192,1408]
  int*   ptok = (int*)(p + 178257920UL);      //     131,072 B
  float* pww  = (float*)(p + 178388992UL);    //     131,072 B
  int*   cnt  = (int*)(p + 178520064UL);      //         256 B
  int*   offs = (int*)(p + 178520320UL);      //         256 B

  hipMemsetAsync(out, 0, (size_t)NTOK * HD * sizeof(float), stream);
  hipMemsetAsync(cnt, 0, NEXP * sizeof(int), stream);

  long n8each = (long)NEXP * ID * HD / 8;     // 2,883,584
  cvt3_kernel<<<33792, 256, 0, stream>>>(wg, wu, wd, wgb, wub, wdb, n8each);

  router_kernel<<<1024, 256, 0, stream>>>(x, gw, xb, out + (size_t)NTOK * HD, cnt, ptok, pww);
  prefix_kernel<<<1, 64, 0, stream>>>(cnt, offs);

  gemm1_kernel<<<dim3(11, 16, 8), 512, 0, stream>>>(xb, wgb, wub, cnt, offs, ptok, hbuf);
  gemm2_kernel<<<dim3(16, 16, 8), 512, 0, stream>>>(hbuf, wdb, cnt, offs, ptok, pww, out);
}